// Round 1
// baseline (362.375 us; speedup 1.0000x reference)
//
#include <hip/hip_runtime.h>
#include <math.h>

// Problem constants
constexpr int L = 32768;
constexpr int H = 256;
constexpr int P = 256;
constexpr int T = 64;      // scan chunk length (== BM so one GEMM row-block == one chunk)
constexpr int NC = L / T;  // 512 chunks

// GEMM tiling
constexpr int BM = 64, BN = 64, BK = 16;
constexpr int LDT = 68;    // padded LDS leading stride (68%32==4 -> 2-way conflicts only, free)

// ---------------------------------------------------------------------------
// Per-p lambda helpers (recomputed per thread; cheap, avoids extra kernels)
// ---------------------------------------------------------------------------
__device__ __forceinline__ void lambda_bar_of(const float* __restrict__ lam,
                                              const float* __restrict__ lstep,
                                              int p, float& lbr, float& lbi) {
  float lr = lam[2 * p], li = lam[2 * p + 1];
  float st = expf(lstep[p]);
  float ea = expf(lr * st);
  lbr = ea * cosf(li * st);
  lbi = ea * sinf(li * st);
}

// ---------------------------------------------------------------------------
// K0a: B_bar[p][h] = ((lambda_bar - 1)/lambda) * B_tilde[p][h]   (planar out)
// ---------------------------------------------------------------------------
__global__ __launch_bounds__(256) void k_prep_bbar(
    const float* __restrict__ lam, const float* __restrict__ lstep,
    const float* __restrict__ Bri, float* __restrict__ Bbr, float* __restrict__ Bbi) {
  int idx = blockIdx.x * 256 + threadIdx.x;  // < P*H
  int p = idx / H;
  float lr = lam[2 * p], li = lam[2 * p + 1];
  float st = expf(lstep[p]);
  float ea = expf(lr * st);
  float lbr = ea * cosf(li * st);
  float lbi = ea * sinf(li * st);
  float den = lr * lr + li * li;
  float inv = 1.0f / den;
  float nr = lbr - 1.0f;
  float fr = (nr * lr + lbi * li) * inv;
  float fi = (lbi * lr - nr * li) * inv;
  float br = Bri[2 * idx], bi = Bri[2 * idx + 1];
  Bbr[idx] = fr * br - fi * bi;
  Bbi[idx] = fr * bi + fi * br;
}

// ---------------------------------------------------------------------------
// K0b: pow[t][p] = lambda_bar^(t+1), closed form (planar, t-major)
// ---------------------------------------------------------------------------
__global__ __launch_bounds__(256) void k_prep_pow(
    const float* __restrict__ lam, const float* __restrict__ lstep,
    float* __restrict__ powr, float* __restrict__ powi) {
  int idx = blockIdx.x * 256 + threadIdx.x;  // < T*P
  int t = idx / P, p = idx % P;
  float lr = lam[2 * p], li = lam[2 * p + 1];
  float st = expf(lstep[p]);
  float e = (float)(t + 1);
  float er = expf(e * lr * st);
  powr[idx] = er * cosf(e * li * st);
  powi[idx] = er * sinf(e * li * st);
}

// ---------------------------------------------------------------------------
// K1: Bu[l][p] = sum_h sig[l][h] * B_bar[p][h]   (re & im share the A tile)
// ---------------------------------------------------------------------------
__global__ __launch_bounds__(256) void k_gemm_bu(
    const float* __restrict__ sig,
    const float* __restrict__ Bbr, const float* __restrict__ Bbi,
    float* __restrict__ Bur, float* __restrict__ Bui) {
  __shared__ float sA[BK * LDT], sBr[BK * LDT], sBi[BK * LDT];
  const int tid = threadIdx.x;
  const int l0 = blockIdx.x * BM;
  const int p0 = blockIdx.y * BN;
  const int r = tid >> 2;          // 0..63 staging row
  const int cq = (tid & 3) * 4;    // 0,4,8,12 staging k-quad
  const int tm = (tid & 15) * 4;   // output row quad
  const int tn = (tid >> 4) * 4;   // output col quad
  float accr[4][4] = {{0}}, acci[4][4] = {{0}};
  for (int k0 = 0; k0 < H; k0 += BK) {
    float4 a4 = *(const float4*)(sig + (l0 + r) * H + k0 + cq);
    float4 b4 = *(const float4*)(Bbr + (p0 + r) * H + k0 + cq);
    float4 c4 = *(const float4*)(Bbi + (p0 + r) * H + k0 + cq);
    __syncthreads();
    sA[(cq + 0) * LDT + r] = a4.x; sA[(cq + 1) * LDT + r] = a4.y;
    sA[(cq + 2) * LDT + r] = a4.z; sA[(cq + 3) * LDT + r] = a4.w;
    sBr[(cq + 0) * LDT + r] = b4.x; sBr[(cq + 1) * LDT + r] = b4.y;
    sBr[(cq + 2) * LDT + r] = b4.z; sBr[(cq + 3) * LDT + r] = b4.w;
    sBi[(cq + 0) * LDT + r] = c4.x; sBi[(cq + 1) * LDT + r] = c4.y;
    sBi[(cq + 2) * LDT + r] = c4.z; sBi[(cq + 3) * LDT + r] = c4.w;
    __syncthreads();
#pragma unroll
    for (int kk = 0; kk < BK; kk++) {
      float4 af = *(const float4*)(sA + kk * LDT + tm);
      float4 bf = *(const float4*)(sBr + kk * LDT + tn);
      float4 cf = *(const float4*)(sBi + kk * LDT + tn);
      float a[4] = {af.x, af.y, af.z, af.w};
      float b[4] = {bf.x, bf.y, bf.z, bf.w};
      float c[4] = {cf.x, cf.y, cf.z, cf.w};
#pragma unroll
      for (int i = 0; i < 4; i++)
#pragma unroll
        for (int j = 0; j < 4; j++) {
          accr[i][j] = fmaf(a[i], b[j], accr[i][j]);
          acci[i][j] = fmaf(a[i], c[j], acci[i][j]);
        }
    }
  }
#pragma unroll
  for (int i = 0; i < 4; i++) {
    float4 o1 = make_float4(accr[i][0], accr[i][1], accr[i][2], accr[i][3]);
    float4 o2 = make_float4(acci[i][0], acci[i][1], acci[i][2], acci[i][3]);
    *(float4*)(Bur + (l0 + tm + i) * P + p0 + tn) = o1;
    *(float4*)(Bui + (l0 + tm + i) * P + p0 + tn) = o2;
  }
}

// ---------------------------------------------------------------------------
// K2: chunk-local scan, in place over Bu. Emits chunk-final state S.
//     One block per chunk; thread = p.
// ---------------------------------------------------------------------------
__global__ __launch_bounds__(256) void k_scan_local(
    const float* __restrict__ lam, const float* __restrict__ lstep,
    float* __restrict__ Bur, float* __restrict__ Bui,
    float* __restrict__ Sr, float* __restrict__ Si) {
  const int c = blockIdx.x;
  const int p = threadIdx.x;
  float lbr, lbi;
  lambda_bar_of(lam, lstep, p, lbr, lbi);
  float xr = 0.f, xi = 0.f;
  int base = c * T * P + p;
#pragma unroll 8
  for (int t = 0; t < T; t++) {
    int idx = base + t * P;
    float br = Bur[idx], bi = Bui[idx];
    float nr = fmaf(lbr, xr, fmaf(-lbi, xi, br));
    float ni = fmaf(lbr, xi, fmaf(lbi, xr, bi));
    Bur[idx] = nr; Bui[idx] = ni;
    xr = nr; xi = ni;
  }
  Sr[c * P + p] = xr;
  Si[c * P + p] = xi;
}

// ---------------------------------------------------------------------------
// K2b: carry scan over chunks. carry[c] = state entering chunk c (x_{cT-1}).
//      Single block, thread = p, register-batched loads to hide latency.
// ---------------------------------------------------------------------------
__global__ __launch_bounds__(256) void k_scan_carry(
    const float* __restrict__ lam, const float* __restrict__ lstep,
    const float* __restrict__ Sr, const float* __restrict__ Si,
    float* __restrict__ car, float* __restrict__ cai) {
  const int p = threadIdx.x;
  float lr = lam[2 * p], li = lam[2 * p + 1];
  float st = expf(lstep[p]);
  float ea = expf((float)T * lr * st);
  float lTr = ea * cosf((float)T * li * st);
  float lTi = ea * sinf((float)T * li * st);
  float cr = 0.f, ci = 0.f;
  for (int c0 = 0; c0 < NC; c0 += 16) {
    float vr[16], vi[16];
#pragma unroll
    for (int u = 0; u < 16; u++) {
      vr[u] = Sr[(c0 + u) * P + p];
      vi[u] = Si[(c0 + u) * P + p];
    }
#pragma unroll
    for (int u = 0; u < 16; u++) {
      car[(c0 + u) * P + p] = cr;
      cai[(c0 + u) * P + p] = ci;
      float nr = fmaf(lTr, cr, fmaf(-lTi, ci, vr[u]));
      float ni = fmaf(lTr, ci, fmaf(lTi, cr, vi[u]));
      cr = nr; ci = ni;
    }
  }
}

// ---------------------------------------------------------------------------
// K3: y[l][h] = sum_p (Ar*Cr - Ai*Ci) + D[h]*sig[l][h]
//     where A = x_local + lambda^(t+1)*carry[c], applied during A staging.
//     BM == T, so each block's row range is exactly one chunk c = blockIdx.x.
// ---------------------------------------------------------------------------
__global__ __launch_bounds__(256) void k_gemm_y(
    const float* __restrict__ Xr, const float* __restrict__ Xi,
    const float* __restrict__ powr, const float* __restrict__ powi,
    const float* __restrict__ car, const float* __restrict__ cai,
    const float* __restrict__ Cri, const float* __restrict__ Dv,
    const float* __restrict__ sig, float* __restrict__ out) {
  __shared__ float sAr[BK * LDT], sAi[BK * LDT], sCr[BK * LDT], sCi[BK * LDT];
  const int tid = threadIdx.x;
  const int c = blockIdx.x;       // chunk index == row block
  const int l0 = c * BM;
  const int h0 = blockIdx.y * BN;
  const int r = tid >> 2;         // staging row (also t index within chunk for A)
  const int q = tid & 3;
  const int cq = q * 4;
  const int tm = (tid & 15) * 4;
  const int tn = (tid >> 4) * 4;
  float acc[4][4] = {{0}};
  for (int k0 = 0; k0 < P; k0 += BK) {
    float4 xr4 = *(const float4*)(Xr + (l0 + r) * P + k0 + cq);
    float4 xi4 = *(const float4*)(Xi + (l0 + r) * P + k0 + cq);
    float4 pr4 = *(const float4*)(powr + r * P + k0 + cq);
    float4 pi4 = *(const float4*)(powi + r * P + k0 + cq);
    float4 cr4 = *(const float4*)(car + c * P + k0 + cq);
    float4 ci4 = *(const float4*)(cai + c * P + k0 + cq);
    // C_tilde: interleaved (H,P,2); one float4 covers two p's (re,im,re,im)
    float4 ca4 = *(const float4*)(Cri + 2 * ((h0 + r) * P + k0 + 2 * q));
    float4 cb4 = *(const float4*)(Cri + 2 * ((h0 + r) * P + k0 + 2 * (q + 4)));
    __syncthreads();
    {
      float xr[4] = {xr4.x, xr4.y, xr4.z, xr4.w};
      float xi_[4] = {xi4.x, xi4.y, xi4.z, xi4.w};
      float pr[4] = {pr4.x, pr4.y, pr4.z, pr4.w};
      float pi_[4] = {pi4.x, pi4.y, pi4.z, pi4.w};
      float crv[4] = {cr4.x, cr4.y, cr4.z, cr4.w};
      float civ[4] = {ci4.x, ci4.y, ci4.z, ci4.w};
#pragma unroll
      for (int j = 0; j < 4; j++) {
        // x_global = x_local + lambda^(t+1) * carry  (complex)
        float arv = xr[j] + pr[j] * crv[j] - pi_[j] * civ[j];
        float aiv = xi_[j] + pr[j] * civ[j] + pi_[j] * crv[j];
        sAr[(cq + j) * LDT + r] = arv;
        sAi[(cq + j) * LDT + r] = aiv;
      }
    }
    sCr[(2 * q + 0) * LDT + r] = ca4.x; sCi[(2 * q + 0) * LDT + r] = ca4.y;
    sCr[(2 * q + 1) * LDT + r] = ca4.z; sCi[(2 * q + 1) * LDT + r] = ca4.w;
    sCr[(2 * (q + 4) + 0) * LDT + r] = cb4.x; sCi[(2 * (q + 4) + 0) * LDT + r] = cb4.y;
    sCr[(2 * (q + 4) + 1) * LDT + r] = cb4.z; sCi[(2 * (q + 4) + 1) * LDT + r] = cb4.w;
    __syncthreads();
#pragma unroll
    for (int kk = 0; kk < BK; kk++) {
      float4 af = *(const float4*)(sAr + kk * LDT + tm);
      float4 bf = *(const float4*)(sAi + kk * LDT + tm);
      float4 cf = *(const float4*)(sCr + kk * LDT + tn);
      float4 df = *(const float4*)(sCi + kk * LDT + tn);
      float ar[4] = {af.x, af.y, af.z, af.w};
      float ai_[4] = {bf.x, bf.y, bf.z, bf.w};
      float cr_[4] = {cf.x, cf.y, cf.z, cf.w};
      float ci_[4] = {df.x, df.y, df.z, df.w};
#pragma unroll
      for (int i = 0; i < 4; i++)
#pragma unroll
        for (int j = 0; j < 4; j++) {
          acc[i][j] = fmaf(ar[i], cr_[j], acc[i][j]);
          acc[i][j] = fmaf(-ai_[i], ci_[j], acc[i][j]);
        }
    }
  }
  float4 d4 = *(const float4*)(Dv + h0 + tn);
  float dd[4] = {d4.x, d4.y, d4.z, d4.w};
#pragma unroll
  for (int i = 0; i < 4; i++) {
    float4 s4 = *(const float4*)(sig + (l0 + tm + i) * H + h0 + tn);
    float sv[4] = {s4.x, s4.y, s4.z, s4.w};
    float4 o;
    o.x = acc[i][0] + dd[0] * sv[0];
    o.y = acc[i][1] + dd[1] * sv[1];
    o.z = acc[i][2] + dd[2] * sv[2];
    o.w = acc[i][3] + dd[3] * sv[3];
    *(float4*)(out + (l0 + tm + i) * H + h0 + tn) = o;
  }
}

// ---------------------------------------------------------------------------
// Launch
// ---------------------------------------------------------------------------
extern "C" void kernel_launch(void* const* d_in, const int* in_sizes, int n_in,
                              void* d_out, int out_size, void* d_ws, size_t ws_size,
                              hipStream_t stream) {
  const float* sig  = (const float*)d_in[0];   // (L,H)
  const float* lam  = (const float*)d_in[1];   // (P,2)
  const float* Bri  = (const float*)d_in[2];   // (P,H,2)
  const float* Cri  = (const float*)d_in[3];   // (H,P,2)
  const float* Dv   = (const float*)d_in[4];   // (H,)
  const float* lst  = (const float*)d_in[5];   // (P,)
  float* out = (float*)d_out;

  // workspace layout (floats); total ~69.9 MB
  float* w    = (float*)d_ws;
  float* Bbr  = w;                  // P*H        = 65536
  float* Bbi  = Bbr  + P * H;
  float* powr = Bbi  + P * H;       // T*P        = 16384
  float* powi = powr + T * P;
  float* Sr   = powi + T * P;       // NC*P       = 131072
  float* Si   = Sr   + NC * P;
  float* car  = Si   + NC * P;
  float* cai  = car  + NC * P;
  float* Bur  = cai  + NC * P;      // L*P        = 8388608
  float* Bui  = Bur  + (size_t)L * P;

  k_prep_bbar<<<P * H / 256, 256, 0, stream>>>(lam, lst, Bri, Bbr, Bbi);
  k_prep_pow<<<T * P / 256, 256, 0, stream>>>(lam, lst, powr, powi);
  dim3 g1(L / BM, P / BN);
  k_gemm_bu<<<g1, 256, 0, stream>>>(sig, Bbr, Bbi, Bur, Bui);
  k_scan_local<<<NC, 256, 0, stream>>>(lam, lst, Bur, Bui, Sr, Si);
  k_scan_carry<<<1, 256, 0, stream>>>(lam, lst, Sr, Si, car, cai);
  dim3 g3(L / BM, H / BN);
  k_gemm_y<<<g3, 256, 0, stream>>>(Bur, Bui, powr, powi, car, cai, Cri, Dv, sig, out);
}

// Round 2
// 192.578 us; speedup vs baseline: 1.8817x; 1.8817x over previous
//
#include <hip/hip_runtime.h>
#include <math.h>

constexpr int L = 32768;
constexpr int H = 256;
constexpr int P = 256;
constexpr int T = 64;        // scan chunk length
constexpr int NC = L / T;    // 512 chunks
constexpr int N1 = 2 * P;    // 512: Bu/X concat width (re | im)

typedef __attribute__((ext_vector_type(8))) short short8;
typedef __attribute__((ext_vector_type(4))) float f32x4;

// ---------------- bf16 helpers (RNE) ----------------
__device__ __forceinline__ unsigned f2bf(float f) {
  unsigned u = __float_as_uint(f);
  return (u + 0x7FFFu + ((u >> 16) & 1u)) >> 16;
}
__device__ __forceinline__ float bf_lo(unsigned u) { return __uint_as_float(u << 16); }
__device__ __forceinline__ float bf_hi(unsigned u) { return __uint_as_float(u & 0xFFFF0000u); }

__device__ __forceinline__ void gload_lds16(const unsigned short* g, unsigned short* l) {
  __builtin_amdgcn_global_load_lds(
      (const __attribute__((address_space(1))) unsigned int*)(g),
      (__attribute__((address_space(3))) unsigned int*)(l), 16, 0, 0);
}

__device__ __forceinline__ void lambda_bar_of(const float* __restrict__ lam,
                                              const float* __restrict__ lstep,
                                              int p, float& lbr, float& lbi) {
  float lr = lam[2 * p], li = lam[2 * p + 1];
  float st = expf(lstep[p]);
  float ea = expf(lr * st);
  lbr = ea * cosf(li * st);
  lbi = ea * sinf(li * st);
}

// ---------------------------------------------------------------------------
// sig fp32 -> bf16 (L*H), 8 elems/thread
// ---------------------------------------------------------------------------
__global__ __launch_bounds__(256) void k_conv_sig(const float* __restrict__ in,
                                                  unsigned short* __restrict__ out) {
  int i = blockIdx.x * 256 + threadIdx.x;  // < L*H/8
  const float4* ip = (const float4*)in;
  float4 a = ip[2 * i], b = ip[2 * i + 1];
  uint4 o;
  o.x = f2bf(a.x) | (f2bf(a.y) << 16);
  o.y = f2bf(a.z) | (f2bf(a.w) << 16);
  o.z = f2bf(b.x) | (f2bf(b.y) << 16);
  o.w = f2bf(b.z) | (f2bf(b.w) << 16);
  ((uint4*)out)[i] = o;
}

// ---------------------------------------------------------------------------
// Build Bcat (512 x 256 bf16): rows 0..255 = Re(B_bar[p]), 256..511 = Im
// Build Ccat (256 x 512 bf16): cols 0..255 = Re(C[h,p]), 256..511 = -Im
// ---------------------------------------------------------------------------
__global__ __launch_bounds__(256) void k_prep(const float* __restrict__ lam,
                                              const float* __restrict__ lstep,
                                              const float* __restrict__ Bri,
                                              const float* __restrict__ Cri,
                                              unsigned short* __restrict__ Bcat,
                                              unsigned short* __restrict__ Ccat) {
  int idx = blockIdx.x * 256 + threadIdx.x;  // < 262144
  if (idx < N1 * H) {
    int n = idx >> 8, k = idx & 255;
    int p = n & (P - 1);
    float lr = lam[2 * p], li = lam[2 * p + 1];
    float st = expf(lstep[p]);
    float ea = expf(lr * st);
    float lbr = ea * cosf(li * st), lbi = ea * sinf(li * st);
    float inv = 1.0f / (lr * lr + li * li);
    float nr = lbr - 1.0f;
    float fr = (nr * lr + lbi * li) * inv;
    float fi = (lbi * lr - nr * li) * inv;
    float br = Bri[2 * (p * H + k)], bi = Bri[2 * (p * H + k) + 1];
    float v = (n < P) ? (fr * br - fi * bi) : (fr * bi + fi * br);
    Bcat[idx] = (unsigned short)f2bf(v);
  } else {
    int j = idx - N1 * H;
    int h = j >> 9, k2 = j & 511;
    int p = k2 & (P - 1);
    float v = (k2 < P) ? Cri[2 * (h * P + p)] : -Cri[2 * (h * P + p) + 1];
    Ccat[j] = (unsigned short)f2bf(v);
  }
}

// ---------------------------------------------------------------------------
// GEMM1: Bu(L x 512, bf16) = sig_bf(L x 256) @ Bcat(512 x 256)^T
// m97 recipe: 128x128 tile, 4 waves (2x2 of 64x64), 16x16x32 MFMA, K-step 32
// ---------------------------------------------------------------------------
__global__ __launch_bounds__(256) void k_gemm1(const unsigned short* __restrict__ A,
                                               const unsigned short* __restrict__ B,
                                               unsigned short* __restrict__ Cout) {
  constexpr int K = 256;
  __shared__ __align__(16) unsigned short sA[128 * 32];
  __shared__ __align__(16) unsigned short sB[128 * 32];
  const int tid = threadIdx.x;
  const int lane = tid & 63;
  const int wave = tid >> 6;
  const int wr = (wave >> 1) * 64, wc = (wave & 1) * 64;
  const int m0 = blockIdx.x * 128, n0 = blockIdx.y * 128;
  const int r0 = tid >> 2, q0 = (tid & 3) * 8;
  const int frow = lane & 15, fk = (lane >> 4) * 8;
  f32x4 acc[4][4];
#pragma unroll
  for (int i = 0; i < 4; i++)
#pragma unroll
    for (int j = 0; j < 4; j++) acc[i][j] = (f32x4){0.f, 0.f, 0.f, 0.f};
  for (int k0 = 0; k0 < K; k0 += 32) {
    if (k0) __syncthreads();
    gload_lds16(A + (size_t)(m0 + r0) * K + k0 + q0, sA + tid * 8);
    gload_lds16(A + (size_t)(m0 + 64 + r0) * K + k0 + q0, sA + 2048 + tid * 8);
    gload_lds16(B + (size_t)(n0 + r0) * K + k0 + q0, sB + tid * 8);
    gload_lds16(B + (size_t)(n0 + 64 + r0) * K + k0 + q0, sB + 2048 + tid * 8);
    __syncthreads();
    short8 af[4], bfr[4];
#pragma unroll
    for (int i = 0; i < 4; i++) af[i] = *(const short8*)(sA + (wr + i * 16 + frow) * 32 + fk);
#pragma unroll
    for (int j = 0; j < 4; j++) bfr[j] = *(const short8*)(sB + (wc + j * 16 + frow) * 32 + fk);
#pragma unroll
    for (int i = 0; i < 4; i++)
#pragma unroll
      for (int j = 0; j < 4; j++)
        acc[i][j] = __builtin_amdgcn_mfma_f32_16x16x32_bf16(af[i], bfr[j], acc[i][j], 0, 0, 0);
  }
  const int crow = wr + (lane >> 4) * 4, ccol = wc + (lane & 15);
#pragma unroll
  for (int i = 0; i < 4; i++)
#pragma unroll
    for (int j = 0; j < 4; j++)
#pragma unroll
      for (int g = 0; g < 4; g++) {
        int row = m0 + crow + i * 16 + g;
        int col = n0 + ccol + j * 16;
        Cout[(size_t)row * N1 + col] = (unsigned short)f2bf(acc[i][j][g]);
      }
}

// ---------------------------------------------------------------------------
// Scan pass 1: chunk-local scan (read-only), emit chunk-final S (fp32)
// 64 threads per chunk, 4 p's per thread, 4 chunks per block
// ---------------------------------------------------------------------------
__global__ __launch_bounds__(256) void k_scan_s(const unsigned short* __restrict__ Bu,
                                                const float* __restrict__ lam,
                                                const float* __restrict__ lstep,
                                                float* __restrict__ Sr, float* __restrict__ Si) {
  const int c = blockIdx.x * 4 + (threadIdx.x >> 6);
  const int pl = (threadIdx.x & 63) * 4;
  float lbr[4], lbi[4];
#pragma unroll
  for (int j = 0; j < 4; j++) lambda_bar_of(lam, lstep, pl + j, lbr[j], lbi[j]);
  float xr[4] = {0.f, 0.f, 0.f, 0.f}, xi[4] = {0.f, 0.f, 0.f, 0.f};
  const unsigned short* base = Bu + (size_t)c * T * N1;
  for (int t = 0; t < T; t++) {
    uint2 re = *(const uint2*)(base + t * N1 + pl);
    uint2 im = *(const uint2*)(base + t * N1 + P + pl);
    float br[4] = {bf_lo(re.x), bf_hi(re.x), bf_lo(re.y), bf_hi(re.y)};
    float bi_[4] = {bf_lo(im.x), bf_hi(im.x), bf_lo(im.y), bf_hi(im.y)};
#pragma unroll
    for (int j = 0; j < 4; j++) {
      float nr = fmaf(lbr[j], xr[j], fmaf(-lbi[j], xi[j], br[j]));
      float ni = fmaf(lbr[j], xi[j], fmaf(lbi[j], xr[j], bi_[j]));
      xr[j] = nr; xi[j] = ni;
    }
  }
  *(float4*)(Sr + c * P + pl) = make_float4(xr[0], xr[1], xr[2], xr[3]);
  *(float4*)(Si + c * P + pl) = make_float4(xi[0], xi[1], xi[2], xi[3]);
}

// ---------------------------------------------------------------------------
// Carry scan over chunks (1 block). car[c] = state entering chunk c.
// ---------------------------------------------------------------------------
__global__ __launch_bounds__(256) void k_carry(const float* __restrict__ lam,
                                               const float* __restrict__ lstep,
                                               const float* __restrict__ Sr,
                                               const float* __restrict__ Si,
                                               float* __restrict__ car, float* __restrict__ cai) {
  const int p = threadIdx.x;
  float lr = lam[2 * p], li = lam[2 * p + 1];
  float st = expf(lstep[p]);
  float ea = expf((float)T * lr * st);
  float lTr = ea * cosf((float)T * li * st);
  float lTi = ea * sinf((float)T * li * st);
  float cr = 0.f, ci = 0.f;
  for (int c0 = 0; c0 < NC; c0 += 16) {
    float vr[16], vi[16];
#pragma unroll
    for (int u = 0; u < 16; u++) {
      vr[u] = Sr[(c0 + u) * P + p];
      vi[u] = Si[(c0 + u) * P + p];
    }
#pragma unroll
    for (int u = 0; u < 16; u++) {
      car[(c0 + u) * P + p] = cr;
      cai[(c0 + u) * P + p] = ci;
      float nr = fmaf(lTr, cr, fmaf(-lTi, ci, vr[u]));
      float ni = fmaf(lTr, ci, fmaf(lTi, cr, vi[u]));
      cr = nr; ci = ni;
    }
  }
}

// ---------------------------------------------------------------------------
// Scan pass 2: re-scan each chunk seeded by carry; write global X (bf16,
// in place over Bu). States stay fp32 in registers.
// ---------------------------------------------------------------------------
__global__ __launch_bounds__(256) void k_scan_x(unsigned short* __restrict__ Bu,
                                                const float* __restrict__ lam,
                                                const float* __restrict__ lstep,
                                                const float* __restrict__ car,
                                                const float* __restrict__ cai) {
  const int c = blockIdx.x * 4 + (threadIdx.x >> 6);
  const int pl = (threadIdx.x & 63) * 4;
  float lbr[4], lbi[4];
#pragma unroll
  for (int j = 0; j < 4; j++) lambda_bar_of(lam, lstep, pl + j, lbr[j], lbi[j]);
  float4 c4r = *(const float4*)(car + c * P + pl);
  float4 c4i = *(const float4*)(cai + c * P + pl);
  float xr[4] = {c4r.x, c4r.y, c4r.z, c4r.w};
  float xi[4] = {c4i.x, c4i.y, c4i.z, c4i.w};
  unsigned short* base = Bu + (size_t)c * T * N1;
  for (int t = 0; t < T; t++) {
    uint2 re = *(const uint2*)(base + t * N1 + pl);
    uint2 im = *(const uint2*)(base + t * N1 + P + pl);
    float br[4] = {bf_lo(re.x), bf_hi(re.x), bf_lo(re.y), bf_hi(re.y)};
    float bi_[4] = {bf_lo(im.x), bf_hi(im.x), bf_lo(im.y), bf_hi(im.y)};
#pragma unroll
    for (int j = 0; j < 4; j++) {
      float nr = fmaf(lbr[j], xr[j], fmaf(-lbi[j], xi[j], br[j]));
      float ni = fmaf(lbr[j], xi[j], fmaf(lbi[j], xr[j], bi_[j]));
      xr[j] = nr; xi[j] = ni;
    }
    uint2 ro, io;
    ro.x = f2bf(xr[0]) | (f2bf(xr[1]) << 16);
    ro.y = f2bf(xr[2]) | (f2bf(xr[3]) << 16);
    io.x = f2bf(xi[0]) | (f2bf(xi[1]) << 16);
    io.y = f2bf(xi[2]) | (f2bf(xi[3]) << 16);
    *(uint2*)(base + t * N1 + pl) = ro;
    *(uint2*)(base + t * N1 + P + pl) = io;
  }
}

// ---------------------------------------------------------------------------
// GEMM2: y(L x 256, fp32) = Xcat(L x 512) @ Ccat(256 x 512)^T + D*u
// ---------------------------------------------------------------------------
__global__ __launch_bounds__(256) void k_gemm2(const unsigned short* __restrict__ A,
                                               const unsigned short* __restrict__ B,
                                               const float* __restrict__ sig,
                                               const float* __restrict__ Dv,
                                               float* __restrict__ out) {
  constexpr int K = 512;
  __shared__ __align__(16) unsigned short sA[128 * 32];
  __shared__ __align__(16) unsigned short sB[128 * 32];
  const int tid = threadIdx.x;
  const int lane = tid & 63;
  const int wave = tid >> 6;
  const int wr = (wave >> 1) * 64, wc = (wave & 1) * 64;
  const int m0 = blockIdx.x * 128, n0 = blockIdx.y * 128;
  const int r0 = tid >> 2, q0 = (tid & 3) * 8;
  const int frow = lane & 15, fk = (lane >> 4) * 8;
  f32x4 acc[4][4];
#pragma unroll
  for (int i = 0; i < 4; i++)
#pragma unroll
    for (int j = 0; j < 4; j++) acc[i][j] = (f32x4){0.f, 0.f, 0.f, 0.f};
  for (int k0 = 0; k0 < K; k0 += 32) {
    if (k0) __syncthreads();
    gload_lds16(A + (size_t)(m0 + r0) * K + k0 + q0, sA + tid * 8);
    gload_lds16(A + (size_t)(m0 + 64 + r0) * K + k0 + q0, sA + 2048 + tid * 8);
    gload_lds16(B + (size_t)(n0 + r0) * K + k0 + q0, sB + tid * 8);
    gload_lds16(B + (size_t)(n0 + 64 + r0) * K + k0 + q0, sB + 2048 + tid * 8);
    __syncthreads();
    short8 af[4], bfr[4];
#pragma unroll
    for (int i = 0; i < 4; i++) af[i] = *(const short8*)(sA + (wr + i * 16 + frow) * 32 + fk);
#pragma unroll
    for (int j = 0; j < 4; j++) bfr[j] = *(const short8*)(sB + (wc + j * 16 + frow) * 32 + fk);
#pragma unroll
    for (int i = 0; i < 4; i++)
#pragma unroll
      for (int j = 0; j < 4; j++)
        acc[i][j] = __builtin_amdgcn_mfma_f32_16x16x32_bf16(af[i], bfr[j], acc[i][j], 0, 0, 0);
  }
  const int crow = wr + (lane >> 4) * 4, ccol = wc + (lane & 15);
  float dcol[4];
#pragma unroll
  for (int j = 0; j < 4; j++) dcol[j] = Dv[n0 + ccol + j * 16];
#pragma unroll
  for (int i = 0; i < 4; i++)
#pragma unroll
    for (int j = 0; j < 4; j++) {
      int col = n0 + ccol + j * 16;
#pragma unroll
      for (int g = 0; g < 4; g++) {
        int row = m0 + crow + i * 16 + g;
        out[(size_t)row * H + col] = acc[i][j][g] + dcol[j] * sig[(size_t)row * H + col];
      }
    }
}

// ---------------------------------------------------------------------------
// Launch
// ---------------------------------------------------------------------------
extern "C" void kernel_launch(void* const* d_in, const int* in_sizes, int n_in,
                              void* d_out, int out_size, void* d_ws, size_t ws_size,
                              hipStream_t stream) {
  const float* sig = (const float*)d_in[0];   // (L,H)
  const float* lam = (const float*)d_in[1];   // (P,2)
  const float* Bri = (const float*)d_in[2];   // (P,H,2)
  const float* Cri = (const float*)d_in[3];   // (H,P,2)
  const float* Dv  = (const float*)d_in[4];   // (H,)
  const float* lst = (const float*)d_in[5];   // (P,)
  float* out = (float*)d_out;

  // workspace layout (~50.5 MB)
  unsigned short* sigbf = (unsigned short*)d_ws;            // L*H
  unsigned short* Bcat  = sigbf + (size_t)L * H;            // N1*H
  unsigned short* Ccat  = Bcat + (size_t)N1 * H;            // H*N1
  unsigned short* Bu    = Ccat + (size_t)H * N1;            // L*N1 (later holds X)
  float* Sr  = (float*)(Bu + (size_t)L * N1);               // NC*P
  float* Si  = Sr + NC * P;
  float* car = Si + NC * P;
  float* cai = car + NC * P;

  k_conv_sig<<<L * H / 8 / 256, 256, 0, stream>>>(sig, sigbf);
  k_prep<<<(2 * N1 * H) / 256, 256, 0, stream>>>(lam, lst, Bri, Cri, Bcat, Ccat);
  dim3 g1(L / 128, N1 / 128);
  k_gemm1<<<g1, 256, 0, stream>>>(sigbf, Bcat, Bu);
  k_scan_s<<<NC / 4, 256, 0, stream>>>(Bu, lam, lst, Sr, Si);
  k_carry<<<1, 256, 0, stream>>>(lam, lst, Sr, Si, car, cai);
  k_scan_x<<<NC / 4, 256, 0, stream>>>(Bu, lam, lst, car, cai);
  dim3 g2(L / 128, H / 128);
  k_gemm2<<<g2, 256, 0, stream>>>(Bu, Ccat, sig, Dv, out);
}

// Round 3
// 174.995 us; speedup vs baseline: 2.0708x; 1.1005x over previous
//
#include <hip/hip_runtime.h>
#include <math.h>

constexpr int L = 32768;
constexpr int H = 256;
constexpr int P = 256;
constexpr int T = 64;        // scan chunk length
constexpr int NC = L / T;    // 512 chunks
constexpr int N1 = 2 * P;    // 512: X concat width, INTERLEAVED col = 2p+{0:re,1:im}
constexpr int LDE = 132;     // epilogue LDS stride (floats)

typedef __attribute__((ext_vector_type(8))) short short8;
typedef __attribute__((ext_vector_type(4))) float f32x4;

// ---------------- bf16 helpers (RNE) ----------------
__device__ __forceinline__ unsigned f2bf(float f) {
  unsigned u = __float_as_uint(f);
  return (u + 0x7FFFu + ((u >> 16) & 1u)) >> 16;
}
__device__ __forceinline__ float bf_lo(unsigned u) { return __uint_as_float(u << 16); }
__device__ __forceinline__ float bf_hi(unsigned u) { return __uint_as_float(u & 0xFFFF0000u); }

__device__ __forceinline__ void gload_lds16(const unsigned short* g, unsigned short* l) {
  __builtin_amdgcn_global_load_lds(
      (const __attribute__((address_space(1))) unsigned int*)(g),
      (__attribute__((address_space(3))) unsigned int*)(l), 16, 0, 0);
}

__device__ __forceinline__ void lambda_bar_of(const float* __restrict__ lam,
                                              const float* __restrict__ lstep,
                                              int p, float& lbr, float& lbi) {
  float lr = lam[2 * p], li = lam[2 * p + 1];
  float st = expf(lstep[p]);
  float ea = expf(lr * st);
  lbr = ea * cosf(li * st);
  lbi = ea * sinf(li * st);
}

// ---------------------------------------------------------------------------
// k_prep: Bcat (512 x 256 bf16, rows interleaved: row 2p=Re(B_bar[p]), 2p+1=Im)
//         Ccat (256 x 512 bf16, cols interleaved: col 2p=Re(C[h,p]), 2p+1=-Im)
//         pow  (T x P fp32 planar): lambda_bar^(t+1)
// ---------------------------------------------------------------------------
__global__ __launch_bounds__(256) void k_prep(const float* __restrict__ lam,
                                              const float* __restrict__ lstep,
                                              const float* __restrict__ Bri,
                                              const float* __restrict__ Cri,
                                              unsigned short* __restrict__ Bcat,
                                              unsigned short* __restrict__ Ccat,
                                              float* __restrict__ powr,
                                              float* __restrict__ powi) {
  int idx = blockIdx.x * 256 + threadIdx.x;  // < 278528
  if (idx < N1 * H) {
    int n = idx >> 8, k = idx & 255;
    int p = n >> 1, comp = n & 1;
    float lr = lam[2 * p], li = lam[2 * p + 1];
    float st = expf(lstep[p]);
    float ea = expf(lr * st);
    float lbr = ea * cosf(li * st), lbi = ea * sinf(li * st);
    float inv = 1.0f / (lr * lr + li * li);
    float nr = lbr - 1.0f;
    float fr = (nr * lr + lbi * li) * inv;
    float fi = (lbi * lr - nr * li) * inv;
    float br = Bri[2 * (p * H + k)], bi = Bri[2 * (p * H + k) + 1];
    float v = (comp == 0) ? (fr * br - fi * bi) : (fr * bi + fi * br);
    Bcat[idx] = (unsigned short)f2bf(v);
  } else if (idx < 2 * N1 * H) {
    int j = idx - N1 * H;
    int h = j >> 9, k2 = j & 511;
    int p = k2 >> 1;
    float v = ((k2 & 1) == 0) ? Cri[2 * (h * P + p)] : -Cri[2 * (h * P + p) + 1];
    Ccat[j] = (unsigned short)f2bf(v);
  } else {
    int r = idx - 2 * N1 * H;  // < T*P
    int t = r >> 8, p = r & 255;
    float lr = lam[2 * p], li = lam[2 * p + 1];
    float st = expf(lstep[p]);
    float e = (float)(t + 1);
    float er = expf(e * lr * st);
    powr[r] = er * cosf(e * li * st);
    powi[r] = er * sinf(e * li * st);
  }
}

// ---------------------------------------------------------------------------
// GEMM1 fused: Bu tile = sig(fp32, converted in-staging) @ Bcat^T, then
// in-block chunk-local scan (fp32) -> write x_local (bf16, interleaved) + S.
// 128x128 tile, 4 waves, 16x16x32 bf16 MFMA. BM=128 = 2 chunks per block.
// ---------------------------------------------------------------------------
__global__ __launch_bounds__(256) void k_gemm1s(const float* __restrict__ sig,
                                                const unsigned short* __restrict__ Bcat,
                                                const float* __restrict__ lam,
                                                const float* __restrict__ lstep,
                                                unsigned short* __restrict__ Xl,
                                                float* __restrict__ Sr,
                                                float* __restrict__ Si) {
  constexpr int K = 256;
  __shared__ __align__(16) float sEpi[128 * LDE];     // 67.6 KB; aliases sA/sB
  unsigned short* sA = (unsigned short*)sEpi;          // 128*32 bf16 = 8 KB
  unsigned short* sB = sA + 128 * 32;                  // 8 KB
  const int tid = threadIdx.x;
  const int lane = tid & 63;
  const int wave = tid >> 6;
  const int wr = (wave >> 1) * 64, wc = (wave & 1) * 64;
  const int m0 = blockIdx.x * 128, n0 = blockIdx.y * 128;
  const int r0 = tid >> 2;            // 0..63
  const int q0 = (tid & 3) * 8;       // elem offset 0,8,16,24
  const int frow = lane & 15, fk = (lane >> 4) * 8;
  f32x4 acc[4][4];
#pragma unroll
  for (int i = 0; i < 4; i++)
#pragma unroll
    for (int j = 0; j < 4; j++) acc[i][j] = (f32x4){0.f, 0.f, 0.f, 0.f};

  for (int k0 = 0; k0 < K; k0 += 32) {
    // prefetch A (fp32) into registers
    float4 a[2][2];
#pragma unroll
    for (int u = 0; u < 2; u++) {
      int row = r0 + u * 64;
      const float* src = sig + (size_t)(m0 + row) * K + k0 + q0;
      a[u][0] = *(const float4*)(src);
      a[u][1] = *(const float4*)(src + 4);
    }
    if (k0) __syncthreads();
    // B: direct global->LDS
    gload_lds16(Bcat + (size_t)(n0 + r0) * K + k0 + q0, sB + tid * 8);
    gload_lds16(Bcat + (size_t)(n0 + 64 + r0) * K + k0 + q0, sB + 2048 + tid * 8);
    // A: convert fp32->bf16, write LDS
#pragma unroll
    for (int u = 0; u < 2; u++) {
      int row = r0 + u * 64;
      uint4 w;
      w.x = f2bf(a[u][0].x) | (f2bf(a[u][0].y) << 16);
      w.y = f2bf(a[u][0].z) | (f2bf(a[u][0].w) << 16);
      w.z = f2bf(a[u][1].x) | (f2bf(a[u][1].y) << 16);
      w.w = f2bf(a[u][1].z) | (f2bf(a[u][1].w) << 16);
      *(uint4*)(sA + row * 32 + q0) = w;
    }
    __syncthreads();
    short8 af[4], bfr[4];
#pragma unroll
    for (int i = 0; i < 4; i++) af[i] = *(const short8*)(sA + (wr + i * 16 + frow) * 32 + fk);
#pragma unroll
    for (int j = 0; j < 4; j++) bfr[j] = *(const short8*)(sB + (wc + j * 16 + frow) * 32 + fk);
#pragma unroll
    for (int i = 0; i < 4; i++)
#pragma unroll
      for (int j = 0; j < 4; j++)
        acc[i][j] = __builtin_amdgcn_mfma_f32_16x16x32_bf16(af[i], bfr[j], acc[i][j], 0, 0, 0);
  }

  // ---- epilogue: dump acc (fp32) to LDS, then chunk-local scan ----
  __syncthreads();  // all MFMA LDS reads done before overwriting sA/sB alias
  const int crow = wr + (lane >> 4) * 4, ccol = wc + (lane & 15);
#pragma unroll
  for (int i = 0; i < 4; i++)
#pragma unroll
    for (int j = 0; j < 4; j++)
#pragma unroll
      for (int g = 0; g < 4; g++)
        sEpi[(crow + i * 16 + g) * LDE + ccol + j * 16] = acc[i][j][g];
  __syncthreads();

  if (tid < 128) {
    const int pl = tid & 63;     // local p within this 128-col tile (64 pairs)
    const int half = tid >> 6;   // which chunk half of the 128 rows
    const int c = blockIdx.x * 2 + half;
    const int gp = (n0 >> 1) + pl;
    float lbr, lbi;
    lambda_bar_of(lam, lstep, gp, lbr, lbi);
    float xr = 0.f, xi = 0.f;
    const float* e = sEpi + (half * 64) * LDE + 2 * pl;
    const size_t gbase = (size_t)(m0 + half * 64) * N1 + n0 + 2 * pl;
    for (int tb = 0; tb < T; tb += 8) {
      float2 v[8];
#pragma unroll
      for (int u = 0; u < 8; u++) v[u] = *(const float2*)(e + (tb + u) * LDE);
      unsigned ov[8];
#pragma unroll
      for (int u = 0; u < 8; u++) {
        float nr = fmaf(lbr, xr, fmaf(-lbi, xi, v[u].x));
        float ni = fmaf(lbr, xi, fmaf(lbi, xr, v[u].y));
        xr = nr; xi = ni;
        ov[u] = f2bf(xr) | (f2bf(xi) << 16);
      }
#pragma unroll
      for (int u = 0; u < 8; u++)
        *(unsigned*)(Xl + gbase + (size_t)(tb + u) * N1) = ov[u];
    }
    Sr[c * P + gp] = xr;
    Si[c * P + gp] = xi;
  }
}

// ---------------------------------------------------------------------------
// Carry scan over chunks (1 block). car[c] = state entering chunk c.
// ---------------------------------------------------------------------------
__global__ __launch_bounds__(256) void k_carry(const float* __restrict__ lam,
                                               const float* __restrict__ lstep,
                                               const float* __restrict__ Sr,
                                               const float* __restrict__ Si,
                                               float* __restrict__ car, float* __restrict__ cai) {
  const int p = threadIdx.x;
  float lr = lam[2 * p], li = lam[2 * p + 1];
  float st = expf(lstep[p]);
  float ea = expf((float)T * lr * st);
  float lTr = ea * cosf((float)T * li * st);
  float lTi = ea * sinf((float)T * li * st);
  float cr = 0.f, ci = 0.f;
  for (int c0 = 0; c0 < NC; c0 += 16) {
    float vr[16], vi[16];
#pragma unroll
    for (int u = 0; u < 16; u++) {
      vr[u] = Sr[(c0 + u) * P + p];
      vi[u] = Si[(c0 + u) * P + p];
    }
#pragma unroll
    for (int u = 0; u < 16; u++) {
      car[(c0 + u) * P + p] = cr;
      cai[(c0 + u) * P + p] = ci;
      float nr = fmaf(lTr, cr, fmaf(-lTi, ci, vr[u]));
      float ni = fmaf(lTr, ci, fmaf(lTi, cr, vi[u]));
      cr = nr; ci = ni;
    }
  }
}

// ---------------------------------------------------------------------------
// GEMM2 fused: y = (x_local + pow*carry) @ Ccat^T + D*u, fixup in A-staging.
// A: manual stage (bf16 x_local + fp32 fixup -> bf16). B: global_load_lds.
// ---------------------------------------------------------------------------
__global__ __launch_bounds__(256) void k_gemm2f(const unsigned short* __restrict__ Xl,
                                                const unsigned short* __restrict__ Ccat,
                                                const float* __restrict__ powr,
                                                const float* __restrict__ powi,
                                                const float* __restrict__ car,
                                                const float* __restrict__ cai,
                                                const float* __restrict__ sig,
                                                const float* __restrict__ Dv,
                                                float* __restrict__ out) {
  constexpr int K = 512;
  __shared__ __align__(16) unsigned short sA[128 * 32];
  __shared__ __align__(16) unsigned short sB[128 * 32];
  const int tid = threadIdx.x;
  const int lane = tid & 63;
  const int wave = tid >> 6;
  const int wr = (wave >> 1) * 64, wc = (wave & 1) * 64;
  const int m0 = blockIdx.x * 128, n0 = blockIdx.y * 128;
  const int bx2 = blockIdx.x * 2;
  const int r0 = tid >> 2;
  const int q0 = (tid & 3) * 8;
  const int frow = lane & 15, fk = (lane >> 4) * 8;
  f32x4 acc[4][4];
#pragma unroll
  for (int i = 0; i < 4; i++)
#pragma unroll
    for (int j = 0; j < 4; j++) acc[i][j] = (f32x4){0.f, 0.f, 0.f, 0.f};

  for (int k0 = 0; k0 < K; k0 += 32) {
    // prefetch x_local + pow/carry slices into registers
    uint4 xa[2];
    float4 pr4[2], pi4[2], cr4[2], ci4[2];
#pragma unroll
    for (int u = 0; u < 2; u++) {
      int row = r0 + u * 64;
      int t = row & 63;
      int c = bx2 + (row >> 6);
      int p0 = (k0 + q0) >> 1;  // 4 consecutive p's (interleaved cols)
      xa[u] = *(const uint4*)(Xl + (size_t)(m0 + row) * K + k0 + q0);
      pr4[u] = *(const float4*)(powr + t * P + p0);
      pi4[u] = *(const float4*)(powi + t * P + p0);
      cr4[u] = *(const float4*)(car + c * P + p0);
      ci4[u] = *(const float4*)(cai + c * P + p0);
    }
    if (k0) __syncthreads();
    gload_lds16(Ccat + (size_t)(n0 + r0) * K + k0 + q0, sB + tid * 8);
    gload_lds16(Ccat + (size_t)(n0 + 64 + r0) * K + k0 + q0, sB + 2048 + tid * 8);
#pragma unroll
    for (int u = 0; u < 2; u++) {
      int row = r0 + u * 64;
      float pr[4] = {pr4[u].x, pr4[u].y, pr4[u].z, pr4[u].w};
      float pi_[4] = {pi4[u].x, pi4[u].y, pi4[u].z, pi4[u].w};
      float cr[4] = {cr4[u].x, cr4[u].y, cr4[u].z, cr4[u].w};
      float ci_[4] = {ci4[u].x, ci4[u].y, ci4[u].z, ci4[u].w};
      unsigned xw[4] = {xa[u].x, xa[u].y, xa[u].z, xa[u].w};
      uint4 w;
      unsigned wo[4];
#pragma unroll
      for (int j = 0; j < 4; j++) {
        float xgr = bf_lo(xw[j]) + (pr[j] * cr[j] - pi_[j] * ci_[j]);
        float xgi = bf_hi(xw[j]) + (pr[j] * ci_[j] + pi_[j] * cr[j]);
        wo[j] = f2bf(xgr) | (f2bf(xgi) << 16);
      }
      w.x = wo[0]; w.y = wo[1]; w.z = wo[2]; w.w = wo[3];
      *(uint4*)(sA + row * 32 + q0) = w;
    }
    __syncthreads();
    short8 af[4], bfr[4];
#pragma unroll
    for (int i = 0; i < 4; i++) af[i] = *(const short8*)(sA + (wr + i * 16 + frow) * 32 + fk);
#pragma unroll
    for (int j = 0; j < 4; j++) bfr[j] = *(const short8*)(sB + (wc + j * 16 + frow) * 32 + fk);
#pragma unroll
    for (int i = 0; i < 4; i++)
#pragma unroll
      for (int j = 0; j < 4; j++)
        acc[i][j] = __builtin_amdgcn_mfma_f32_16x16x32_bf16(af[i], bfr[j], acc[i][j], 0, 0, 0);
  }

  const int crow = wr + (lane >> 4) * 4, ccol = wc + (lane & 15);
  float dcol[4];
#pragma unroll
  for (int j = 0; j < 4; j++) dcol[j] = Dv[n0 + ccol + j * 16];
#pragma unroll
  for (int i = 0; i < 4; i++)
#pragma unroll
    for (int j = 0; j < 4; j++) {
      int col = n0 + ccol + j * 16;
#pragma unroll
      for (int g = 0; g < 4; g++) {
        int row = m0 + crow + i * 16 + g;
        out[(size_t)row * H + col] = acc[i][j][g] + dcol[j] * sig[(size_t)row * H + col];
      }
    }
}

// ---------------------------------------------------------------------------
// Launch
// ---------------------------------------------------------------------------
extern "C" void kernel_launch(void* const* d_in, const int* in_sizes, int n_in,
                              void* d_out, int out_size, void* d_ws, size_t ws_size,
                              hipStream_t stream) {
  const float* sig = (const float*)d_in[0];   // (L,H)
  const float* lam = (const float*)d_in[1];   // (P,2)
  const float* Bri = (const float*)d_in[2];   // (P,H,2)
  const float* Cri = (const float*)d_in[3];   // (H,P,2)
  const float* Dv  = (const float*)d_in[4];   // (H,)
  const float* lst = (const float*)d_in[5];   // (P,)
  float* out = (float*)d_out;

  // workspace layout (~35 MB)
  unsigned short* Bcat = (unsigned short*)d_ws;             // N1*H bf16
  unsigned short* Ccat = Bcat + (size_t)N1 * H;             // H*N1 bf16
  unsigned short* Xl   = Ccat + (size_t)H * N1;             // L*N1 bf16 (x_local)
  float* powr = (float*)(Xl + (size_t)L * N1);              // T*P
  float* powi = powr + T * P;
  float* Sr   = powi + T * P;                               // NC*P
  float* Si   = Sr + NC * P;
  float* car  = Si + NC * P;
  float* cai  = car + NC * P;

  k_prep<<<(2 * N1 * H + T * P) / 256, 256, 0, stream>>>(lam, lst, Bri, Cri,
                                                         Bcat, Ccat, powr, powi);
  dim3 g1(L / 128, N1 / 128);
  k_gemm1s<<<g1, 256, 0, stream>>>(sig, Bcat, lam, lst, Xl, Sr, Si);
  k_carry<<<1, 256, 0, stream>>>(lam, lst, Sr, Si, car, cai);
  dim3 g2(L / 128, H / 128);
  k_gemm2f<<<g2, 256, 0, stream>>>(Xl, Ccat, powr, powi, car, cai, sig, Dv, out);
}

// Round 4
// 167.997 us; speedup vs baseline: 2.1570x; 1.0417x over previous
//
#include <hip/hip_runtime.h>
#include <math.h>

constexpr int L = 32768;
constexpr int H = 256;
constexpr int P = 256;
constexpr int T = 64;        // scan chunk length == GEMM row tile
constexpr int NC = L / T;    // 512 chunks
constexpr int N1 = 2 * P;    // 512: X concat width, INTERLEAVED col = 2p+{0:re,1:im}
constexpr int LDE = 132;     // epilogue LDS stride (floats)

typedef __attribute__((ext_vector_type(8))) short short8;
typedef __attribute__((ext_vector_type(4))) float f32x4;

// ---------------- bf16 helpers (RNE) ----------------
__device__ __forceinline__ unsigned f2bf(float f) {
  unsigned u = __float_as_uint(f);
  return (u + 0x7FFFu + ((u >> 16) & 1u)) >> 16;
}
__device__ __forceinline__ float bf_lo(unsigned u) { return __uint_as_float(u << 16); }
__device__ __forceinline__ float bf_hi(unsigned u) { return __uint_as_float(u & 0xFFFF0000u); }

__device__ __forceinline__ void gload_lds16(const unsigned short* g, unsigned short* l) {
  __builtin_amdgcn_global_load_lds(
      (const __attribute__((address_space(1))) unsigned int*)(g),
      (__attribute__((address_space(3))) unsigned int*)(l), 16, 0, 0);
}

__device__ __forceinline__ void lambda_bar_of(const float* __restrict__ lam,
                                              const float* __restrict__ lstep,
                                              int p, float& lbr, float& lbi) {
  float lr = lam[2 * p], li = lam[2 * p + 1];
  float st = expf(lstep[p]);
  float ea = expf(lr * st);
  lbr = ea * cosf(li * st);
  lbi = ea * sinf(li * st);
}

// ---------------------------------------------------------------------------
// k_prep: Bcat (512 x 256 bf16, rows interleaved: row 2p=Re(B_bar[p]), 2p+1=Im)
//         Ccat (256 x 512 bf16, cols interleaved: col 2p=Re(C[h,p]), 2p+1=-Im)
//         pow  (T x P fp32 planar): lambda_bar^(t+1)
// ---------------------------------------------------------------------------
__global__ __launch_bounds__(256) void k_prep(const float* __restrict__ lam,
                                              const float* __restrict__ lstep,
                                              const float* __restrict__ Bri,
                                              const float* __restrict__ Cri,
                                              unsigned short* __restrict__ Bcat,
                                              unsigned short* __restrict__ Ccat,
                                              float* __restrict__ powr,
                                              float* __restrict__ powi) {
  int idx = blockIdx.x * 256 + threadIdx.x;  // < 278528
  if (idx < N1 * H) {
    int n = idx >> 8, k = idx & 255;
    int p = n >> 1, comp = n & 1;
    float lr = lam[2 * p], li = lam[2 * p + 1];
    float st = expf(lstep[p]);
    float ea = expf(lr * st);
    float lbr = ea * cosf(li * st), lbi = ea * sinf(li * st);
    float inv = 1.0f / (lr * lr + li * li);
    float nr = lbr - 1.0f;
    float fr = (nr * lr + lbi * li) * inv;
    float fi = (lbi * lr - nr * li) * inv;
    float br = Bri[2 * (p * H + k)], bi = Bri[2 * (p * H + k) + 1];
    float v = (comp == 0) ? (fr * br - fi * bi) : (fr * bi + fi * br);
    Bcat[idx] = (unsigned short)f2bf(v);
  } else if (idx < 2 * N1 * H) {
    int j = idx - N1 * H;
    int h = j >> 9, k2 = j & 511;
    int p = k2 >> 1;
    float v = ((k2 & 1) == 0) ? Cri[2 * (h * P + p)] : -Cri[2 * (h * P + p) + 1];
    Ccat[j] = (unsigned short)f2bf(v);
  } else {
    int r = idx - 2 * N1 * H;  // < T*P
    int t = r >> 8, p = r & 255;
    float lr = lam[2 * p], li = lam[2 * p + 1];
    float st = expf(lstep[p]);
    float e = (float)(t + 1);
    float er = expf(e * lr * st);
    powr[r] = er * cosf(e * li * st);
    powi[r] = er * sinf(e * li * st);
  }
}

// ---------------------------------------------------------------------------
// GEMM1 fused: 64x128 tile (1 chunk x 64 pairs). A = sig fp32 -> bf16 staged,
// B = Bcat via global_load_lds. Epilogue: in-block chunk scan -> Xl + S.
// grid (NC, N1/128) = (512, 4); 4 blocks/CU (LDS 33.8 KB).
// ---------------------------------------------------------------------------
__global__ __launch_bounds__(256) void k_gemm1s(const float* __restrict__ sig,
                                                const unsigned short* __restrict__ Bcat,
                                                const float* __restrict__ lam,
                                                const float* __restrict__ lstep,
                                                unsigned short* __restrict__ Xl,
                                                float* __restrict__ Sr,
                                                float* __restrict__ Si) {
  constexpr int K = 256;
  __shared__ __align__(16) float sEpi[T * LDE];        // 33.8 KB, aliases sA/sB
  unsigned short* sA = (unsigned short*)sEpi;           // 64*32 bf16 = 4 KB
  unsigned short* sB = sA + 64 * 32;                    // 128*32 bf16 = 8 KB
  const int tid = threadIdx.x;
  const int lane = tid & 63;
  const int wave = tid >> 6;
  const int wc = wave * 32;
  const int c = blockIdx.x;
  const int m0 = c * 64;
  const int n0 = blockIdx.y * 128;
  const int r0 = tid >> 2;            // 0..63
  const int q0 = (tid & 3) * 8;       // 0,8,16,24
  const int frow = lane & 15, fk = (lane >> 4) * 8;
  f32x4 acc[4][2];
#pragma unroll
  for (int i = 0; i < 4; i++)
#pragma unroll
    for (int j = 0; j < 2; j++) acc[i][j] = (f32x4){0.f, 0.f, 0.f, 0.f};

  for (int k0 = 0; k0 < K; k0 += 32) {
    // prefetch A (fp32) into registers
    const float* src = sig + (size_t)(m0 + r0) * K + k0 + q0;
    float4 a0 = *(const float4*)(src);
    float4 a1 = *(const float4*)(src + 4);
    if (k0) __syncthreads();
    gload_lds16(Bcat + (size_t)(n0 + r0) * K + k0 + q0, sB + tid * 8);
    gload_lds16(Bcat + (size_t)(n0 + 64 + r0) * K + k0 + q0, sB + 2048 + tid * 8);
    uint4 w;
    w.x = f2bf(a0.x) | (f2bf(a0.y) << 16);
    w.y = f2bf(a0.z) | (f2bf(a0.w) << 16);
    w.z = f2bf(a1.x) | (f2bf(a1.y) << 16);
    w.w = f2bf(a1.z) | (f2bf(a1.w) << 16);
    *(uint4*)(sA + r0 * 32 + q0) = w;
    __syncthreads();
    short8 af[4], bfr[2];
#pragma unroll
    for (int i = 0; i < 4; i++) af[i] = *(const short8*)(sA + (i * 16 + frow) * 32 + fk);
#pragma unroll
    for (int j = 0; j < 2; j++) bfr[j] = *(const short8*)(sB + (wc + j * 16 + frow) * 32 + fk);
#pragma unroll
    for (int i = 0; i < 4; i++)
#pragma unroll
      for (int j = 0; j < 2; j++)
        acc[i][j] = __builtin_amdgcn_mfma_f32_16x16x32_bf16(af[i], bfr[j], acc[i][j], 0, 0, 0);
  }

  // ---- epilogue: dump acc to LDS (t x col), then chunk-local scan ----
  __syncthreads();
  const int crow = (lane >> 4) * 4, ccol = wc + (lane & 15);
#pragma unroll
  for (int i = 0; i < 4; i++)
#pragma unroll
    for (int j = 0; j < 2; j++)
#pragma unroll
      for (int g = 0; g < 4; g++)
        sEpi[(crow + i * 16 + g) * LDE + ccol + j * 16] = acc[i][j][g];
  __syncthreads();

  if (tid < 64) {
    const int pl = tid;                 // local pair 0..63
    const int gp = (n0 >> 1) + pl;      // global p
    float lbr, lbi;
    lambda_bar_of(lam, lstep, gp, lbr, lbi);
    float xr = 0.f, xi = 0.f;
    const float* e = sEpi + 2 * pl;
    const size_t gbase = (size_t)m0 * N1 + n0 + 2 * pl;
    for (int tb = 0; tb < T; tb += 8) {
      float2 v[8];
#pragma unroll
      for (int u = 0; u < 8; u++) v[u] = *(const float2*)(e + (tb + u) * LDE);
      unsigned ov[8];
#pragma unroll
      for (int u = 0; u < 8; u++) {
        float nr = fmaf(lbr, xr, fmaf(-lbi, xi, v[u].x));
        float ni = fmaf(lbr, xi, fmaf(lbi, xr, v[u].y));
        xr = nr; xi = ni;
        ov[u] = f2bf(xr) | (f2bf(xi) << 16);
      }
#pragma unroll
      for (int u = 0; u < 8; u++)
        *(unsigned*)(Xl + gbase + (size_t)(tb + u) * N1) = ov[u];
    }
    Sr[c * P + gp] = xr;
    Si[c * P + gp] = xi;
  }
}

// ---------------------------------------------------------------------------
// Carry scan over chunks (1 block, 256 threads = p). Batch-32 loads.
// ---------------------------------------------------------------------------
__global__ __launch_bounds__(256) void k_carry(const float* __restrict__ lam,
                                               const float* __restrict__ lstep,
                                               const float* __restrict__ Sr,
                                               const float* __restrict__ Si,
                                               float* __restrict__ car, float* __restrict__ cai) {
  const int p = threadIdx.x;
  float lr = lam[2 * p], li = lam[2 * p + 1];
  float st = expf(lstep[p]);
  float ea = expf((float)T * lr * st);
  float lTr = ea * cosf((float)T * li * st);
  float lTi = ea * sinf((float)T * li * st);
  float cr = 0.f, ci = 0.f;
  for (int c0 = 0; c0 < NC; c0 += 32) {
    float vr[32], vi[32];
#pragma unroll
    for (int u = 0; u < 32; u++) {
      vr[u] = Sr[(c0 + u) * P + p];
      vi[u] = Si[(c0 + u) * P + p];
    }
#pragma unroll
    for (int u = 0; u < 32; u++) {
      car[(c0 + u) * P + p] = cr;
      cai[(c0 + u) * P + p] = ci;
      float nr = fmaf(lTr, cr, fmaf(-lTi, ci, vr[u]));
      float ni = fmaf(lTr, ci, fmaf(lTi, cr, vi[u]));
      cr = nr; ci = ni;
    }
  }
}

// ---------------------------------------------------------------------------
// GEMM2 fused: 64x128 tile (1 chunk x 128 h's). A = x_local + pow*carry
// (fixup in staging, car uniform per block). grid (NC, H/128) = (512, 2).
// ---------------------------------------------------------------------------
__global__ __launch_bounds__(256) void k_gemm2f(const unsigned short* __restrict__ Xl,
                                                const unsigned short* __restrict__ Ccat,
                                                const float* __restrict__ powr,
                                                const float* __restrict__ powi,
                                                const float* __restrict__ car,
                                                const float* __restrict__ cai,
                                                const float* __restrict__ sig,
                                                const float* __restrict__ Dv,
                                                float* __restrict__ out) {
  constexpr int K = 512;
  __shared__ __align__(16) unsigned short sA[64 * 32];   // 4 KB
  __shared__ __align__(16) unsigned short sB[128 * 32];  // 8 KB
  const int tid = threadIdx.x;
  const int lane = tid & 63;
  const int wave = tid >> 6;
  const int wc = wave * 32;
  const int c = blockIdx.x;
  const int m0 = c * 64;
  const int n0 = blockIdx.y * 128;
  const int r0 = tid >> 2;            // row = t (0..63)
  const int q0 = (tid & 3) * 8;       // 8 shorts = 4 pairs
  const int frow = lane & 15, fk = (lane >> 4) * 8;
  f32x4 acc[4][2];
#pragma unroll
  for (int i = 0; i < 4; i++)
#pragma unroll
    for (int j = 0; j < 2; j++) acc[i][j] = (f32x4){0.f, 0.f, 0.f, 0.f};

  for (int k0 = 0; k0 < K; k0 += 32) {
    int p0 = (k0 + q0) >> 1;  // 4 consecutive p's
    uint4 xa = *(const uint4*)(Xl + (size_t)(m0 + r0) * K + k0 + q0);
    float4 pr4 = *(const float4*)(powr + r0 * P + p0);
    float4 pi4 = *(const float4*)(powi + r0 * P + p0);
    float4 cr4 = *(const float4*)(car + c * P + p0);
    float4 ci4 = *(const float4*)(cai + c * P + p0);
    if (k0) __syncthreads();
    gload_lds16(Ccat + (size_t)(n0 + r0) * K + k0 + q0, sB + tid * 8);
    gload_lds16(Ccat + (size_t)(n0 + 64 + r0) * K + k0 + q0, sB + 2048 + tid * 8);
    {
      float pr[4] = {pr4.x, pr4.y, pr4.z, pr4.w};
      float pi_[4] = {pi4.x, pi4.y, pi4.z, pi4.w};
      float crv[4] = {cr4.x, cr4.y, cr4.z, cr4.w};
      float civ[4] = {ci4.x, ci4.y, ci4.z, ci4.w};
      unsigned xw[4] = {xa.x, xa.y, xa.z, xa.w};
      unsigned wo[4];
#pragma unroll
      for (int j = 0; j < 4; j++) {
        float xgr = bf_lo(xw[j]) + (pr[j] * crv[j] - pi_[j] * civ[j]);
        float xgi = bf_hi(xw[j]) + (pr[j] * civ[j] + pi_[j] * crv[j]);
        wo[j] = f2bf(xgr) | (f2bf(xgi) << 16);
      }
      uint4 w;
      w.x = wo[0]; w.y = wo[1]; w.z = wo[2]; w.w = wo[3];
      *(uint4*)(sA + r0 * 32 + q0) = w;
    }
    __syncthreads();
    short8 af[4], bfr[2];
#pragma unroll
    for (int i = 0; i < 4; i++) af[i] = *(const short8*)(sA + (i * 16 + frow) * 32 + fk);
#pragma unroll
    for (int j = 0; j < 2; j++) bfr[j] = *(const short8*)(sB + (wc + j * 16 + frow) * 32 + fk);
#pragma unroll
    for (int i = 0; i < 4; i++)
#pragma unroll
      for (int j = 0; j < 2; j++)
        acc[i][j] = __builtin_amdgcn_mfma_f32_16x16x32_bf16(af[i], bfr[j], acc[i][j], 0, 0, 0);
  }

  const int crow = (lane >> 4) * 4, ccol = wc + (lane & 15);
  float dcol[2];
#pragma unroll
  for (int j = 0; j < 2; j++) dcol[j] = Dv[n0 + ccol + j * 16];
#pragma unroll
  for (int i = 0; i < 4; i++)
#pragma unroll
    for (int j = 0; j < 2; j++) {
      int col = n0 + ccol + j * 16;
#pragma unroll
      for (int g = 0; g < 4; g++) {
        int row = m0 + crow + i * 16 + g;
        out[(size_t)row * H + col] = acc[i][j][g] + dcol[j] * sig[(size_t)row * H + col];
      }
    }
}

// ---------------------------------------------------------------------------
// Launch
// ---------------------------------------------------------------------------
extern "C" void kernel_launch(void* const* d_in, const int* in_sizes, int n_in,
                              void* d_out, int out_size, void* d_ws, size_t ws_size,
                              hipStream_t stream) {
  const float* sig = (const float*)d_in[0];   // (L,H)
  const float* lam = (const float*)d_in[1];   // (P,2)
  const float* Bri = (const float*)d_in[2];   // (P,H,2)
  const float* Cri = (const float*)d_in[3];   // (H,P,2)
  const float* Dv  = (const float*)d_in[4];   // (H,)
  const float* lst = (const float*)d_in[5];   // (P,)
  float* out = (float*)d_out;

  // workspace layout (~35 MB)
  unsigned short* Bcat = (unsigned short*)d_ws;             // N1*H bf16
  unsigned short* Ccat = Bcat + (size_t)N1 * H;             // H*N1 bf16
  unsigned short* Xl   = Ccat + (size_t)H * N1;             // L*N1 bf16 (x_local)
  float* powr = (float*)(Xl + (size_t)L * N1);              // T*P
  float* powi = powr + T * P;
  float* Sr   = powi + T * P;                               // NC*P
  float* Si   = Sr + NC * P;
  float* car  = Si + NC * P;
  float* cai  = car + NC * P;

  k_prep<<<(2 * N1 * H + T * P) / 256, 256, 0, stream>>>(lam, lst, Bri, Cri,
                                                         Bcat, Ccat, powr, powi);
  dim3 g1(NC, N1 / 128);
  k_gemm1s<<<g1, 256, 0, stream>>>(sig, Bcat, lam, lst, Xl, Sr, Si);
  k_carry<<<1, 256, 0, stream>>>(lam, lst, Sr, Si, car, cai);
  dim3 g2(NC, H / 128);
  k_gemm2f<<<g2, 256, 0, stream>>>(Xl, Ccat, powr, powi, car, cai, sig, Dv, out);
}

// Round 5
// 153.790 us; speedup vs baseline: 2.3563x; 1.0924x over previous
//
#include <hip/hip_runtime.h>
#include <math.h>

constexpr int L = 32768;
constexpr int H = 256;
constexpr int P = 256;
constexpr int T = 64;        // scan chunk length
constexpr int NC = L / T;    // 512 chunks
constexpr int N1 = 2 * P;    // 512: X concat width, INTERLEAVED col = 2p+{0:re,1:im}
constexpr int LDA = 40;      // padded LDS A row stride (shorts): conflict-free frag reads
constexpr int LDEP = 130;    // epilogue LDS row stride (floats)

typedef __attribute__((ext_vector_type(8))) short short8;
typedef __attribute__((ext_vector_type(4))) float f32x4;

// ---------------- bf16 helpers (RNE) ----------------
__device__ __forceinline__ unsigned f2bf(float f) {
  unsigned u = __float_as_uint(f);
  return (u + 0x7FFFu + ((u >> 16) & 1u)) >> 16;
}
__device__ __forceinline__ float bf_lo(unsigned u) { return __uint_as_float(u << 16); }
__device__ __forceinline__ float bf_hi(unsigned u) { return __uint_as_float(u & 0xFFFF0000u); }

__device__ __forceinline__ void gload_lds16(const unsigned short* g, unsigned short* l) {
  __builtin_amdgcn_global_load_lds(
      (const __attribute__((address_space(1))) unsigned int*)(g),
      (__attribute__((address_space(3))) unsigned int*)(l), 16, 0, 0);
}

__device__ __forceinline__ void lambda_bar_of(const float* __restrict__ lam,
                                              const float* __restrict__ lstep,
                                              int p, float& lbr, float& lbi) {
  float lr = lam[2 * p], li = lam[2 * p + 1];
  float st = expf(lstep[p]);
  float ea = expf(lr * st);
  lbr = ea * cosf(li * st);
  lbi = ea * sinf(li * st);
}

// ---------------------------------------------------------------------------
// k_prep: Bcat (512 x 256 bf16, rows interleaved: row 2p=Re(B_bar[p]), 2p+1=Im)
//         Ccat (256 x 512 bf16, cols interleaved: col 2p=Re(C[h,p]), 2p+1=-Im)
//         pow  (T x P fp32 planar): lambda_bar^(t+1)
// ---------------------------------------------------------------------------
__global__ __launch_bounds__(256) void k_prep(const float* __restrict__ lam,
                                              const float* __restrict__ lstep,
                                              const float* __restrict__ Bri,
                                              const float* __restrict__ Cri,
                                              unsigned short* __restrict__ Bcat,
                                              unsigned short* __restrict__ Ccat,
                                              float* __restrict__ powr,
                                              float* __restrict__ powi) {
  int idx = blockIdx.x * 256 + threadIdx.x;  // < 278528
  if (idx < N1 * H) {
    int n = idx >> 8, k = idx & 255;
    int p = n >> 1, comp = n & 1;
    float lr = lam[2 * p], li = lam[2 * p + 1];
    float st = expf(lstep[p]);
    float ea = expf(lr * st);
    float lbr = ea * cosf(li * st), lbi = ea * sinf(li * st);
    float inv = 1.0f / (lr * lr + li * li);
    float nr = lbr - 1.0f;
    float fr = (nr * lr + lbi * li) * inv;
    float fi = (lbi * lr - nr * li) * inv;
    float br = Bri[2 * (p * H + k)], bi = Bri[2 * (p * H + k) + 1];
    float v = (comp == 0) ? (fr * br - fi * bi) : (fr * bi + fi * br);
    Bcat[idx] = (unsigned short)f2bf(v);
  } else if (idx < 2 * N1 * H) {
    int j = idx - N1 * H;
    int h = j >> 9, k2 = j & 511;
    int p = k2 >> 1;
    float v = ((k2 & 1) == 0) ? Cri[2 * (h * P + p)] : -Cri[2 * (h * P + p) + 1];
    Ccat[j] = (unsigned short)f2bf(v);
  } else {
    int r = idx - 2 * N1 * H;  // < T*P
    int t = r >> 8, p = r & 255;
    float lr = lam[2 * p], li = lam[2 * p + 1];
    float st = expf(lstep[p]);
    float e = (float)(t + 1);
    float er = expf(e * lr * st);
    powr[r] = er * cosf(e * li * st);
    powi[r] = er * sinf(e * li * st);
  }
}

// ---------------------------------------------------------------------------
// GEMM1 fused: 128x128 tile (2 chunks), dbuf LDS, ONE barrier per 32-K step.
// A = sig fp32 -> bf16 manual staging (padded LDS rows). B via global_load_lds.
// Epilogue: per-chunk LDS dump + in-block scan -> Xl (bf16 interleaved) + S.
// grid (L/128, N1/128) = (256, 4).
// ---------------------------------------------------------------------------
__global__ __launch_bounds__(256) void k_gemm1s(const float* __restrict__ sig,
                                                const unsigned short* __restrict__ Bcat,
                                                const float* __restrict__ lam,
                                                const float* __restrict__ lstep,
                                                unsigned short* __restrict__ Xl,
                                                float* __restrict__ Sr,
                                                float* __restrict__ Si) {
  constexpr int K = 256, NIT = K / 32;
  __shared__ __align__(16) char smem[36864];
  unsigned short* sA[2] = {(unsigned short*)smem, (unsigned short*)smem + 5120};
  unsigned short* sB[2] = {(unsigned short*)smem + 10240, (unsigned short*)smem + 14336};
  float* sEpi = (float*)smem;
  const int tid = threadIdx.x;
  const int lane = tid & 63;
  const int wave = tid >> 6;
  const int wr = (wave >> 1) * 64, wc = (wave & 1) * 64;
  const int m0 = blockIdx.x * 128, n0 = blockIdx.y * 128;
  const int ar = tid >> 1, aq = (tid & 1) * 16;   // A staging: row 0..127, 16-elem half
  const int br = tid >> 2, bq = (tid & 3) * 8;    // B staging
  const int frow = lane & 15, fk = (lane >> 4) * 8;
  f32x4 acc[4][4];
#pragma unroll
  for (int i = 0; i < 4; i++)
#pragma unroll
    for (int j = 0; j < 4; j++) acc[i][j] = (f32x4){0.f, 0.f, 0.f, 0.f};

  float4 aR[4];
  const float* abase = sig + (size_t)(m0 + ar) * K + aq;
#define LOAD_A(k0) { const float* s_ = abase + (k0); \
    aR[0] = *(const float4*)(s_); aR[1] = *(const float4*)(s_ + 4); \
    aR[2] = *(const float4*)(s_ + 8); aR[3] = *(const float4*)(s_ + 12); }
#define WRITE_A(buf) { uint4 w0, w1; \
    w0.x = f2bf(aR[0].x) | (f2bf(aR[0].y) << 16); w0.y = f2bf(aR[0].z) | (f2bf(aR[0].w) << 16); \
    w0.z = f2bf(aR[1].x) | (f2bf(aR[1].y) << 16); w0.w = f2bf(aR[1].z) | (f2bf(aR[1].w) << 16); \
    w1.x = f2bf(aR[2].x) | (f2bf(aR[2].y) << 16); w1.y = f2bf(aR[2].z) | (f2bf(aR[2].w) << 16); \
    w1.z = f2bf(aR[3].x) | (f2bf(aR[3].y) << 16); w1.w = f2bf(aR[3].z) | (f2bf(aR[3].w) << 16); \
    *(uint4*)(sA[buf] + ar * LDA + aq) = w0; *(uint4*)(sA[buf] + ar * LDA + aq + 8) = w1; }
#define ISSUE_B(k0, buf) { \
    gload_lds16(Bcat + (size_t)(n0 + br) * K + (k0) + bq, sB[buf] + tid * 8); \
    gload_lds16(Bcat + (size_t)(n0 + 64 + br) * K + (k0) + bq, sB[buf] + 2048 + tid * 8); }

  // prologue
  LOAD_A(0);
  ISSUE_B(0, 0);
  WRITE_A(0);
  LOAD_A(32);
  __syncthreads();
#pragma unroll
  for (int it = 0; it < NIT; it++) {
    const int cur = it & 1, nxt = cur ^ 1;
    if (it + 1 < NIT) {
      WRITE_A(nxt);
      ISSUE_B((it + 1) * 32, nxt);
      if (it + 2 < NIT) LOAD_A((it + 2) * 32);
    }
    short8 af[4], bf[4];
#pragma unroll
    for (int i = 0; i < 4; i++) af[i] = *(const short8*)(sA[cur] + (wr + i * 16 + frow) * LDA + fk);
#pragma unroll
    for (int j = 0; j < 4; j++) bf[j] = *(const short8*)(sB[cur] + (wc + j * 16 + frow) * 32 + fk);
#pragma unroll
    for (int i = 0; i < 4; i++)
#pragma unroll
      for (int j = 0; j < 4; j++)
        acc[i][j] = __builtin_amdgcn_mfma_f32_16x16x32_bf16(af[i], bf[j], acc[i][j], 0, 0, 0);
    __syncthreads();
  }

  // ---- epilogue: per chunk-half: dump rows to LDS, scan, store ----
  const int crow = (lane >> 4) * 4, ccol = wc + (lane & 15);
#pragma unroll
  for (int half = 0; half < 2; half++) {
    if ((wave >> 1) == half) {
#pragma unroll
      for (int i = 0; i < 4; i++)
#pragma unroll
        for (int j = 0; j < 4; j++)
#pragma unroll
          for (int g = 0; g < 4; g++)
            sEpi[(crow + i * 16 + g) * LDEP + ccol + j * 16] = acc[i][j][g];
    }
    __syncthreads();
    if (tid < 64) {
      const int pl = tid;
      const int gp = (n0 >> 1) + pl;
      const int c = blockIdx.x * 2 + half;
      float lbr, lbi;
      lambda_bar_of(lam, lstep, gp, lbr, lbi);
      float xr = 0.f, xi = 0.f;
      const float* e = sEpi + 2 * pl;
      const size_t gbase = (size_t)(m0 + half * 64) * N1 + n0 + 2 * pl;
      for (int tb = 0; tb < T; tb += 8) {
        float2 v[8];
#pragma unroll
        for (int u = 0; u < 8; u++) v[u] = *(const float2*)(e + (tb + u) * LDEP);
        unsigned ov[8];
#pragma unroll
        for (int u = 0; u < 8; u++) {
          float nr = fmaf(lbr, xr, fmaf(-lbi, xi, v[u].x));
          float ni = fmaf(lbr, xi, fmaf(lbi, xr, v[u].y));
          xr = nr; xi = ni;
          ov[u] = f2bf(xr) | (f2bf(xi) << 16);
        }
#pragma unroll
        for (int u = 0; u < 8; u++)
          *(unsigned*)(Xl + gbase + (size_t)(tb + u) * N1) = ov[u];
      }
      Sr[c * P + gp] = xr;
      Si[c * P + gp] = xi;
    }
    __syncthreads();
  }
#undef LOAD_A
#undef WRITE_A
#undef ISSUE_B
}

// ---------------------------------------------------------------------------
// Parallel carry scan: 256 blocks (one per p) x 64 threads (1 wave).
// Lane t handles chunks [8t, 8t+8): local Horner -> wave segment-scan via
// shfl_up -> exclusive carry -> apply + store.
// ---------------------------------------------------------------------------
__global__ __launch_bounds__(64) void k_carry2(const float* __restrict__ lam,
                                               const float* __restrict__ lstep,
                                               const float* __restrict__ Sr,
                                               const float* __restrict__ Si,
                                               float* __restrict__ car, float* __restrict__ cai) {
  const int p = blockIdx.x;
  const int t = threadIdx.x;  // 0..63
  float lr = lam[2 * p], li = lam[2 * p + 1];
  float st = expf(lstep[p]);
  float eT = expf((float)T * lr * st);
  float lTr = eT * cosf((float)T * li * st);
  float lTi = eT * sinf((float)T * li * st);
  // local segment over 8 chunks
  float vr[8], vi[8];
#pragma unroll
  for (int u = 0; u < 8; u++) {
    vr[u] = Sr[(t * 8 + u) * P + p];
    vi[u] = Si[(t * 8 + u) * P + p];
  }
  float Br = 0.f, Bi = 0.f;
#pragma unroll
  for (int u = 0; u < 8; u++) {
    float nr = fmaf(lTr, Br, fmaf(-lTi, Bi, vr[u]));
    float ni = fmaf(lTr, Bi, fmaf(lTi, Br, vi[u]));
    Br = nr; Bi = ni;
  }
  float e8 = expf(8.0f * (float)T * lr * st);
  float Ar = e8 * cosf(8.0f * (float)T * li * st);
  float Ai = e8 * sinf(8.0f * (float)T * li * st);
  // inclusive wave scan of (A,B) under (A2,B2)o(A1,B1) = (A1*A2, B2 + A2*B1)
#pragma unroll
  for (int d = 1; d < 64; d <<= 1) {
    float Aor = __shfl_up(Ar, d), Aoi = __shfl_up(Ai, d);
    float Bor = __shfl_up(Br, d), Boi = __shfl_up(Bi, d);
    if (t >= d) {
      float nBr = Ar * Bor - Ai * Boi + Br;
      float nBi = Ar * Boi + Ai * Bor + Bi;
      float nAr = Aor * Ar - Aoi * Ai;
      float nAi = Aor * Ai + Aoi * Ar;
      Br = nBr; Bi = nBi; Ar = nAr; Ai = nAi;
    }
  }
  // exclusive: state entering this lane's first chunk
  float cr = __shfl_up(Br, 1), ci = __shfl_up(Bi, 1);
  if (t == 0) { cr = 0.f; ci = 0.f; }
#pragma unroll
  for (int u = 0; u < 8; u++) {
    car[(t * 8 + u) * P + p] = cr;
    cai[(t * 8 + u) * P + p] = ci;
    float nr = fmaf(lTr, cr, fmaf(-lTi, ci, vr[u]));
    float ni = fmaf(lTr, ci, fmaf(lTi, cr, vi[u]));
    cr = nr; ci = ni;
  }
}

// ---------------------------------------------------------------------------
// GEMM2 fused: 128x128 tile (2 chunks), dbuf LDS, ONE barrier per 32-K step.
// A = x_local(bf16) + pow*carry fixup (fp32), manual staged. B via load_lds.
// grid (L/128, H/128) = (256, 2).
// ---------------------------------------------------------------------------
__global__ __launch_bounds__(256) void k_gemm2f(const unsigned short* __restrict__ Xl,
                                                const unsigned short* __restrict__ Ccat,
                                                const float* __restrict__ powr,
                                                const float* __restrict__ powi,
                                                const float* __restrict__ car,
                                                const float* __restrict__ cai,
                                                const float* __restrict__ sig,
                                                const float* __restrict__ Dv,
                                                float* __restrict__ out) {
  constexpr int K = 512, NIT = K / 32;
  __shared__ __align__(16) char smem[36864];
  unsigned short* sA[2] = {(unsigned short*)smem, (unsigned short*)smem + 5120};
  unsigned short* sB[2] = {(unsigned short*)smem + 10240, (unsigned short*)smem + 14336};
  const int tid = threadIdx.x;
  const int lane = tid & 63;
  const int wave = tid >> 6;
  const int wr = (wave >> 1) * 64, wc = (wave & 1) * 64;
  const int m0 = blockIdx.x * 128, n0 = blockIdx.y * 128;
  const int ar = tid >> 1, aq = (tid & 1) * 16;   // row 0..127, 16-short half (8 pairs)
  const int t_ = ar & 63;
  const int cc = blockIdx.x * 2 + (ar >> 6);
  const int br = tid >> 2, bq = (tid & 3) * 8;
  const int frow = lane & 15, fk = (lane >> 4) * 8;
  f32x4 acc[4][4];
#pragma unroll
  for (int i = 0; i < 4; i++)
#pragma unroll
    for (int j = 0; j < 4; j++) acc[i][j] = (f32x4){0.f, 0.f, 0.f, 0.f};

  uint4 x0, x1;
  float4 pr0, pr1, pi0, pi1, cr0, cr1, ci0, ci1;
  const unsigned short* xbase = Xl + (size_t)(m0 + ar) * N1 + aq;
  const float* prb = powr + t_ * P;
  const float* pib = powi + t_ * P;
  const float* crb = car + cc * P;
  const float* cib = cai + cc * P;
#define LOAD_A2(k0) { int p0_ = ((k0) >> 1) + (tid & 1) * 8; \
    x0 = *(const uint4*)(xbase + (k0)); x1 = *(const uint4*)(xbase + (k0) + 8); \
    pr0 = *(const float4*)(prb + p0_); pr1 = *(const float4*)(prb + p0_ + 4); \
    pi0 = *(const float4*)(pib + p0_); pi1 = *(const float4*)(pib + p0_ + 4); \
    cr0 = *(const float4*)(crb + p0_); cr1 = *(const float4*)(crb + p0_ + 4); \
    ci0 = *(const float4*)(cib + p0_); ci1 = *(const float4*)(cib + p0_ + 4); }
#define WRITE_A2(buf) { \
    unsigned xw[8] = {x0.x, x0.y, x0.z, x0.w, x1.x, x1.y, x1.z, x1.w}; \
    float pr_[8] = {pr0.x, pr0.y, pr0.z, pr0.w, pr1.x, pr1.y, pr1.z, pr1.w}; \
    float pi_[8] = {pi0.x, pi0.y, pi0.z, pi0.w, pi1.x, pi1.y, pi1.z, pi1.w}; \
    float cr_[8] = {cr0.x, cr0.y, cr0.z, cr0.w, cr1.x, cr1.y, cr1.z, cr1.w}; \
    float ci_[8] = {ci0.x, ci0.y, ci0.z, ci0.w, ci1.x, ci1.y, ci1.z, ci1.w}; \
    unsigned wo[8]; \
    _Pragma("unroll") for (int j_ = 0; j_ < 8; j_++) { \
      float xgr = bf_lo(xw[j_]) + (pr_[j_] * cr_[j_] - pi_[j_] * ci_[j_]); \
      float xgi = bf_hi(xw[j_]) + (pr_[j_] * ci_[j_] + pi_[j_] * cr_[j_]); \
      wo[j_] = f2bf(xgr) | (f2bf(xgi) << 16); } \
    uint4 w0, w1; \
    w0.x = wo[0]; w0.y = wo[1]; w0.z = wo[2]; w0.w = wo[3]; \
    w1.x = wo[4]; w1.y = wo[5]; w1.z = wo[6]; w1.w = wo[7]; \
    *(uint4*)(sA[buf] + ar * LDA + aq) = w0; *(uint4*)(sA[buf] + ar * LDA + aq + 8) = w1; }
#define ISSUE_B2(k0, buf) { \
    gload_lds16(Ccat + (size_t)(n0 + br) * K + (k0) + bq, sB[buf] + tid * 8); \
    gload_lds16(Ccat + (size_t)(n0 + 64 + br) * K + (k0) + bq, sB[buf] + 2048 + tid * 8); }

  LOAD_A2(0);
  ISSUE_B2(0, 0);
  WRITE_A2(0);
  LOAD_A2(32);
  __syncthreads();
#pragma unroll
  for (int it = 0; it < NIT; it++) {
    const int cur = it & 1, nxt = cur ^ 1;
    if (it + 1 < NIT) {
      WRITE_A2(nxt);
      ISSUE_B2((it + 1) * 32, nxt);
      if (it + 2 < NIT) LOAD_A2((it + 2) * 32);
    }
    short8 af[4], bf[4];
#pragma unroll
    for (int i = 0; i < 4; i++) af[i] = *(const short8*)(sA[cur] + (wr + i * 16 + frow) * LDA + fk);
#pragma unroll
    for (int j = 0; j < 4; j++) bf[j] = *(const short8*)(sB[cur] + (wc + j * 16 + frow) * 32 + fk);
#pragma unroll
    for (int i = 0; i < 4; i++)
#pragma unroll
      for (int j = 0; j < 4; j++)
        acc[i][j] = __builtin_amdgcn_mfma_f32_16x16x32_bf16(af[i], bf[j], acc[i][j], 0, 0, 0);
    __syncthreads();
  }

  const int crow = wr + (lane >> 4) * 4, ccol = wc + (lane & 15);
  float dcol[4];
#pragma unroll
  for (int j = 0; j < 4; j++) dcol[j] = Dv[n0 + ccol + j * 16];
#pragma unroll
  for (int i = 0; i < 4; i++)
#pragma unroll
    for (int j = 0; j < 4; j++) {
      int col = n0 + ccol + j * 16;
#pragma unroll
      for (int g = 0; g < 4; g++) {
        int row = m0 + crow + i * 16 + g;
        out[(size_t)row * H + col] = acc[i][j][g] + dcol[j] * sig[(size_t)row * H + col];
      }
    }
#undef LOAD_A2
#undef WRITE_A2
#undef ISSUE_B2
}

// ---------------------------------------------------------------------------
// Launch
// ---------------------------------------------------------------------------
extern "C" void kernel_launch(void* const* d_in, const int* in_sizes, int n_in,
                              void* d_out, int out_size, void* d_ws, size_t ws_size,
                              hipStream_t stream) {
  const float* sig = (const float*)d_in[0];   // (L,H)
  const float* lam = (const float*)d_in[1];   // (P,2)
  const float* Bri = (const float*)d_in[2];   // (P,H,2)
  const float* Cri = (const float*)d_in[3];   // (H,P,2)
  const float* Dv  = (const float*)d_in[4];   // (H,)
  const float* lst = (const float*)d_in[5];   // (P,)
  float* out = (float*)d_out;

  // workspace layout (~35 MB)
  unsigned short* Bcat = (unsigned short*)d_ws;             // N1*H bf16
  unsigned short* Ccat = Bcat + (size_t)N1 * H;             // H*N1 bf16
  unsigned short* Xl   = Ccat + (size_t)H * N1;             // L*N1 bf16 (x_local)
  float* powr = (float*)(Xl + (size_t)L * N1);              // T*P
  float* powi = powr + T * P;
  float* Sr   = powi + T * P;                               // NC*P
  float* Si   = Sr + NC * P;
  float* car  = Si + NC * P;
  float* cai  = car + NC * P;

  k_prep<<<(2 * N1 * H + T * P) / 256, 256, 0, stream>>>(lam, lst, Bri, Cri,
                                                         Bcat, Ccat, powr, powi);
  dim3 g1(L / 128, N1 / 128);
  k_gemm1s<<<g1, 256, 0, stream>>>(sig, Bcat, lam, lst, Xl, Sr, Si);
  k_carry2<<<NC / 2, 64, 0, stream>>>(lam, lst, Sr, Si, car, cai);
  dim3 g2(L / 128, H / 128);
  k_gemm2f<<<g2, 256, 0, stream>>>(Xl, Ccat, powr, powi, car, cai, sig, Dv, out);
}